// Round 19
// baseline (341.453 us; speedup 1.0000x reference)
//
#include <hip/hip_runtime.h>

#define NN 50000
#define NE 800000
#define FDIM 256
#define SCAN_BLOCKS 196  // ceil(50000/256)
#define MMG 782          // ceil(NN/64)  (bd kernels)
#define NTILE 1563       // ceil(NN/32)  (row tiles for k_mm)
#define GRIDX 391        // persistent k_mm blocks: 4 balanced rounds over 1563 tiles
#define HIST_BLOCKS 782  // ceil(NE/1024), 4 edges/thread

typedef __attribute__((ext_vector_type(8))) short short8v;
typedef __attribute__((ext_vector_type(4))) float float4v;

__device__ __forceinline__ unsigned short f2bf(float f) {
  unsigned u = __float_as_uint(f);
  unsigned r = (u + 0x7fffu + ((u >> 16) & 1u)) >> 16;
  return (unsigned short)r;
}
__device__ __forceinline__ float bf2f(unsigned short b) {
  return __uint_as_float(((unsigned)b) << 16);
}

// ---------------- CSR build ----------------

__global__ __launch_bounds__(256) void k_hist(const int* __restrict__ dst, int* __restrict__ deg16,
                                              int* __restrict__ rank) {
  const int base = blockIdx.x * 1024 + threadIdx.x;
  #pragma unroll
  for (int k = 0; k < 4; k++) {
    int e = base + k * 256;
    if (e < NE) rank[e] = atomicAdd(&deg16[dst[e] << 4], 1);
  }
}

__device__ __forceinline__ int block_incl_scan(int v, int* wsum) {
  const int tid = threadIdx.x;
  const int lane = tid & 63;
  const int w = tid >> 6;
  int incl = v;
  #pragma unroll
  for (int off = 1; off < 64; off <<= 1) {
    int tmp = __shfl_up(incl, off, 64);
    if (lane >= off) incl += tmp;
  }
  if (lane == 63) wsum[w] = incl;
  __syncthreads();
  int woff = 0;
  #pragma unroll
  for (int k = 0; k < 3; k++)
    if (k < w) woff += wsum[k];
  return woff + incl;
}

__global__ __launch_bounds__(256) void k_scan_a(const int* __restrict__ deg16, int* __restrict__ partial) {
  __shared__ int wsum[4];
  int i = blockIdx.x * 256 + threadIdx.x;
  int v = (i < NN) ? deg16[i << 4] : 0;
  int incl = block_incl_scan(v, wsum);
  if (threadIdx.x == 255) partial[blockIdx.x] = incl;
}

// blocks 0..255: weight prep (fp32->bf16, transposed); block 256: scan of partials
__global__ __launch_bounds__(256) void k_scanb_wprep(int* __restrict__ partial, int* __restrict__ offs,
                                                     const float* __restrict__ W1_0, const float* __restrict__ encW,
                                                     const float* __restrict__ W1_1, const float* __restrict__ W2_0,
                                                     const float* __restrict__ W2_1, unsigned short* __restrict__ Bt1,
                                                     unsigned short* __restrict__ BtE, unsigned short* __restrict__ Wb11,
                                                     unsigned short* __restrict__ Wb20, unsigned short* __restrict__ Wb21) {
  if (blockIdx.x == 256) {
    __shared__ int wsum[4];
    int tid = threadIdx.x;
    int v = (tid < SCAN_BLOCKS) ? partial[tid] : 0;
    int incl = block_incl_scan(v, wsum);
    if (tid < SCAN_BLOCKS) partial[tid] = incl - v;  // exclusive
    if (tid == 255) offs[NN] = incl;                 // total == NE
    return;
  }
  const int t = blockIdx.x;   // output col
  const int k = threadIdx.x;  // reduction index
  const int c = t >> 6, j = t & 63;
  Bt1[t * 256 + k] = f2bf(W1_0[c * 16384 + k * 64 + j]);
  BtE[t * 256 + k] = f2bf(encW[k * 256 + t]);
  if (k < 64) {
    Wb11[c * 4096 + j * 64 + k] = f2bf(W1_1[c * 4096 + k * 64 + j]);
    Wb20[c * 4096 + j * 64 + k] = f2bf(W2_0[c * 4096 + k * 64 + j]);
    Wb21[c * 4096 + j * 64 + k] = f2bf(W2_1[c * 4096 + k * 64 + j]);
  }
}

__global__ __launch_bounds__(256) void k_scan_c(const int* __restrict__ deg16, const int* __restrict__ partial,
                                                int* __restrict__ offs) {
  __shared__ int wsum[4];
  int i = blockIdx.x * 256 + threadIdx.x;
  int v = (i < NN) ? deg16[i << 4] : 0;
  int incl = block_incl_scan(v, wsum);
  int excl = partial[blockIdx.x] + incl - v;
  if (i < NN) offs[i] = excl;
}

// ---------------- atomic-free edge-record fill: 4 edges/thread ----------------
__global__ __launch_bounds__(256) void k_fill(const int* __restrict__ srcA, const int* __restrict__ dstA,
                                              const float* __restrict__ ew, const int* __restrict__ rank,
                                              const int* __restrict__ offs, int4* __restrict__ recs) {
  const int base = blockIdx.x * 1024 + threadIdx.x;
  #pragma unroll
  for (int k = 0; k < 4; k++) {
    int e = base + k * 256;
    if (e < NE) {
      int sA = srcA[e];
      int dA = dstA[e];
      int rk = rank[e];
      unsigned p01 = (unsigned)f2bf(ew[e]) | ((unsigned)f2bf(ew[NE + e]) << 16);
      unsigned p23 = (unsigned)f2bf(ew[2 * NE + e]) | ((unsigned)f2bf(ew[3 * NE + e]) << 16);
      recs[offs[dA] + rk] = make_int4(sA, (int)p01, (int)p23, 0);
    }
  }
}

// ---------------- persistent weight-stationary MFMA GEMM, P1 AND enc in one block ----------------
// 512 threads: waves 0..3 hold Bt1 fragments (P cols), waves 4..7 hold BtE (enc cols).
// x staged once per tile (double-buffered LDS); epilogues serialize through xs[cur].
__global__ __launch_bounds__(512) void k_mm(const float* __restrict__ x,
                                            const unsigned short* __restrict__ Bt1,
                                            const unsigned short* __restrict__ BtE,
                                            const float* __restrict__ encb,
                                            unsigned short* __restrict__ Pout,
                                            float* __restrict__ encout) {
  __shared__ __align__(16) unsigned short xs[2][32][264];  // 2 x 16896B
  const int tid = threadIdx.x;  // 0..511
  const int lane = tid & 63;
  const int w = tid >> 6;       // 0..7
  const int isE = w >> 2;       // waves 0-3: P, waves 4-7: enc
  const int colw = (w & 3) * 64;
  const int lr = lane & 15;
  const int lk = (lane >> 4) * 8;
  const int rbase = (lane >> 4) * 4;

  const unsigned short* Bt = isE ? BtE : Bt1;

  // B resident in registers: 32 fragments x 16B/lane = 128 VGPRs
  short8v bfrag[8][4];
  #pragma unroll
  for (int ks8 = 0; ks8 < 8; ks8++)
    #pragma unroll
    for (int ct = 0; ct < 4; ct++)
      bfrag[ks8][ct] = *reinterpret_cast<const short8v*>(
          Bt + (size_t)(colw + ct * 16 + lr) * 256 + ks8 * 32 + lk);

  float bv[4];
  #pragma unroll
  for (int ct = 0; ct < 4; ct++) bv[ct] = isE ? encb[colw + ct * 16 + lr] : 0.f;

  // prologue: stage first tile into buffer 0 (2048 float4 / 512 threads = 4 iters)
  {
    const int row0 = blockIdx.x * 32;
    #pragma unroll
    for (int it = 0; it < 4; it++) {
      int idx = it * 512 + tid;
      int grow = row0 + (idx >> 6);
      if (grow >= NN) grow = NN - 1;
      float4 v = *reinterpret_cast<const float4*>(x + (size_t)grow * 256 + (idx & 63) * 4);
      ushort4 o;
      o.x = f2bf(v.x); o.y = f2bf(v.y); o.z = f2bf(v.z); o.w = f2bf(v.w);
      *reinterpret_cast<ushort4*>(&xs[0][idx >> 6][(idx & 63) * 4]) = o;
    }
  }
  __syncthreads();

  int cur = 0;
  for (int t = blockIdx.x; t < NTILE; t += GRIDX, cur ^= 1) {
    const int row0 = t * 32;
    const int t2 = t + GRIDX;
    const bool hasNext = t2 < NTILE;

    // issue next tile's global loads (latency hides under MFMAs below)
    float4 xv[4];
    if (hasNext) {
      #pragma unroll
      for (int it = 0; it < 4; it++) {
        int idx = it * 512 + tid;
        int grow = t2 * 32 + (idx >> 6);
        if (grow >= NN) grow = NN - 1;
        xv[it] = *reinterpret_cast<const float4*>(x + (size_t)grow * 256 + (idx & 63) * 4);
      }
    }

    // MFMA: A from LDS, B from registers
    float4v acc[2][4];
    #pragma unroll
    for (int rt = 0; rt < 2; rt++)
      #pragma unroll
      for (int ct = 0; ct < 4; ct++) acc[rt][ct] = (float4v){0.f, 0.f, 0.f, 0.f};

    #pragma unroll
    for (int ks8 = 0; ks8 < 8; ks8++) {
      short8v a[2];
      #pragma unroll
      for (int rt = 0; rt < 2; rt++)
        a[rt] = *reinterpret_cast<const short8v*>(&xs[cur][rt * 16 + lr][ks8 * 32 + lk]);
      #pragma unroll
      for (int rt = 0; rt < 2; rt++)
        #pragma unroll
        for (int ct = 0; ct < 4; ct++)
          acc[rt][ct] = __builtin_amdgcn_mfma_f32_16x16x32_bf16(a[rt], bfrag[ks8][ct], acc[rt][ct], 0, 0, 0);
    }

    __syncthreads();  // xs[cur] reads done

    // stage next tile into the other buffer
    if (hasNext) {
      #pragma unroll
      for (int it = 0; it < 4; it++) {
        int idx = it * 512 + tid;
        ushort4 o;
        o.x = f2bf(xv[it].x); o.y = f2bf(xv[it].y); o.z = f2bf(xv[it].z); o.w = f2bf(xv[it].w);
        *reinterpret_cast<ushort4*>(&xs[cur ^ 1][idx >> 6][(idx & 63) * 4]) = o;
      }
    }

    // ---- epilogue phase 1: P (bf16) through xs[cur] ----
    if (!isE) {
      #pragma unroll
      for (int rt = 0; rt < 2; rt++)
        #pragma unroll
        for (int ct = 0; ct < 4; ct++) {
          const int col = colw + ct * 16 + lr;
          #pragma unroll
          for (int r = 0; r < 4; r++) xs[cur][rt * 16 + rbase + r][col] = f2bf(acc[rt][ct][r]);
        }
    }
    __syncthreads();
    #pragma unroll
    for (int it = 0; it < 2; it++) {
      int idx = it * 512 + tid;  // 32 rows x 32 chunks of 8 shorts = 1024
      int row = idx >> 5;
      int p = idx & 31;
      if (row0 + row < NN)
        *reinterpret_cast<short8v*>(Pout + (size_t)(row0 + row) * 256 + p * 8) =
            *reinterpret_cast<const short8v*>(&xs[cur][row][p * 8]);
    }
    __syncthreads();

    // ---- epilogue phase 2: enc (fp32), two 128-col phases through xs[cur] ----
    float (*cs)[132] = reinterpret_cast<float(*)[132]>(&xs[cur][0][0]);  // 32*132*4 = 16896B
    #pragma unroll
    for (int ph = 0; ph < 2; ph++) {
      if (isE && (colw >> 7) == ph) {
        #pragma unroll
        for (int rt = 0; rt < 2; rt++)
          #pragma unroll
          for (int ct = 0; ct < 4; ct++) {
            const int col = colw + ct * 16 + lr - ph * 128;
            #pragma unroll
            for (int r = 0; r < 4; r++) cs[rt * 16 + rbase + r][col] = acc[rt][ct][r] + bv[ct];
          }
      }
      __syncthreads();
      #pragma unroll
      for (int it = 0; it < 2; it++) {
        int idx = it * 512 + tid;  // 32 rows x 32 float4 chunks = 1024
        int row = idx >> 5;
        int p = idx & 31;
        if (row0 + row < NN)
          *reinterpret_cast<float4*>(encout + (size_t)(row0 + row) * 256 + ph * 128 + p * 4) =
              *reinterpret_cast<const float4*>(&cs[row][p * 4]);
      }
      __syncthreads();
    }
  }
}

// ---------------- aggregation: one wave per node, half-waves on even/odd edges ----------------
__global__ __launch_bounds__(256) void k_agg(const unsigned short* __restrict__ P,
                                             const int* __restrict__ offs, const int4* __restrict__ recs,
                                             const float* __restrict__ b1, unsigned short* __restrict__ Rb) {
  const int lane = threadIdx.x & 63;
  const int wid = threadIdx.x >> 6;
  const int i = blockIdx.x * 4 + wid;  // grid = NN/4 exactly
  const int half = lane >> 5;
  const int l32 = lane & 31;
  const int col0 = l32 * 8;
  const int c = l32 >> 3;

  const int es = offs[i], ee = offs[i + 1];
  float acc[8];
  #pragma unroll
  for (int j = 0; j < 8; j++) acc[j] = 0.f;

  for (int base = es; base < ee; base += 16) {
    int sq[8];
    float wq[8];
    #pragma unroll
    for (int q = 0; q < 8; q++) {
      int e = base + 2 * q + half;
      bool valid = e < ee;
      int4 rv = recs[valid ? e : es];
      sq[q] = rv.x;
      unsigned p = (c < 2) ? (unsigned)rv.y : (unsigned)rv.z;
      unsigned short wb = (c & 1) ? (unsigned short)(p >> 16) : (unsigned short)(p & 0xffff);
      wq[q] = valid ? bf2f(wb) : 0.f;
    }
    short8v pq[8];
    #pragma unroll
    for (int q = 0; q < 8; q++)
      pq[q] = *reinterpret_cast<const short8v*>(P + (size_t)sq[q] * 256 + col0);
    #pragma unroll
    for (int q = 0; q < 8; q++)
      #pragma unroll
      for (int j = 0; j < 8; j++)
        acc[j] = fmaf(wq[q], bf2f((unsigned short)pq[q][j]), acc[j]);
  }

  #pragma unroll
  for (int j = 0; j < 8; j++) acc[j] += __shfl_xor(acc[j], 32);

  if (half == 0) {
    short8v ps = *reinterpret_cast<const short8v*>(P + (size_t)i * 256 + col0);
    float4 b4a = *reinterpret_cast<const float4*>(b1 + col0);
    float4 b4b = *reinterpret_cast<const float4*>(b1 + col0 + 4);
    float bb[8] = {b4a.x, b4a.y, b4a.z, b4a.w, b4b.x, b4b.y, b4b.z, b4b.w};
    short8v out;
    #pragma unroll
    for (int j = 0; j < 8; j++) {
      float r = bf2f((unsigned short)ps[j]) + acc[j] + bb[j];
      out[j] = (short)f2bf(r > 0.f ? r : 0.f);
    }
    *reinterpret_cast<short8v*>(Rb + (size_t)i * 256 + col0) = out;
  }
}

// ---------------- block-diag K=64 GEMM: stats-only pass (b2 cancels in BN) ----------------
__global__ __launch_bounds__(256) void k_bd_stats(const unsigned short* __restrict__ A,
                                                  const unsigned short* __restrict__ Wz,
                                                  float* __restrict__ bnsum, float* __restrict__ bnsq) {
  const int lane = threadIdx.x & 63;
  const int c = threadIdx.x >> 6;
  const int row0 = blockIdx.x * 64;
  const int lr = lane & 15;
  const int lk = (lane >> 4) * 8;

  const unsigned short* Aptr[4];
  #pragma unroll
  for (int rt = 0; rt < 4; rt++) {
    int row = row0 + rt * 16 + lr;
    if (row >= NN) row = NN - 1;
    Aptr[rt] = A + (size_t)row * 256 + c * 64 + lk;
  }

  float4v acc[4][4];
  #pragma unroll
  for (int rt = 0; rt < 4; rt++)
    #pragma unroll
    for (int ct = 0; ct < 4; ct++) acc[rt][ct] = (float4v){0.f, 0.f, 0.f, 0.f};

  #pragma unroll
  for (int ks = 0; ks < 64; ks += 32) {
    short8v a[4], b[4];
    #pragma unroll
    for (int rt = 0; rt < 4; rt++) a[rt] = *reinterpret_cast<const short8v*>(Aptr[rt] + ks);
    #pragma unroll
    for (int ct = 0; ct < 4; ct++)
      b[ct] = *reinterpret_cast<const short8v*>(Wz + (size_t)c * 4096 + (ct * 16 + lr) * 64 + ks + lk);
    #pragma unroll
    for (int rt = 0; rt < 4; rt++)
      #pragma unroll
      for (int ct = 0; ct < 4; ct++)
        acc[rt][ct] = __builtin_amdgcn_mfma_f32_16x16x32_bf16(a[rt], b[ct], acc[rt][ct], 0, 0, 0);
  }

  #pragma unroll
  for (int ct = 0; ct < 4; ct++) {
    const int col = c * 64 + ct * 16 + lr;
    float s1 = 0.f, s2 = 0.f;
    #pragma unroll
    for (int rt = 0; rt < 4; rt++) {
      #pragma unroll
      for (int r = 0; r < 4; r++) {
        const int row = row0 + rt * 16 + (lane >> 4) * 4 + r;
        if (row < NN) {
          float v = acc[rt][ct][r];
          s1 += v;
          s2 += v * v;
        }
      }
    }
    s1 += __shfl_xor(s1, 16); s1 += __shfl_xor(s1, 32);
    s2 += __shfl_xor(s2, 16); s2 += __shfl_xor(s2, 32);
    if (lane < 16) {
      atomicAdd(&bnsum[col], s1);
      atomicAdd(&bnsq[col], s2);
    }
  }
}

// ---------------- block-diag K=64 GEMM: recompute + BN + relu; optional fused P2 ----------------
template <int WITH_P2>
__global__ __launch_bounds__(256) void k_bd_bn(const unsigned short* __restrict__ A,
                                               const unsigned short* __restrict__ Wz,
                                               const float* __restrict__ bnsum, const float* __restrict__ bnsq,
                                               const float* __restrict__ g, const float* __restrict__ bt,
                                               const unsigned short* __restrict__ Wp,
                                               float* __restrict__ Hout, unsigned short* __restrict__ P2out) {
  __shared__ __align__(16) unsigned short h_lds[64][264];  // stride 528B
  const int lane = threadIdx.x & 63;
  const int c = threadIdx.x >> 6;
  const int row0 = blockIdx.x * 64;
  const int lr = lane & 15;
  const int lk = (lane >> 4) * 8;
  const int rbase = (lane >> 4) * 4;

  const unsigned short* Aptr[4];
  #pragma unroll
  for (int rt = 0; rt < 4; rt++) {
    int row = row0 + rt * 16 + lr;
    if (row >= NN) row = NN - 1;
    Aptr[rt] = A + (size_t)row * 256 + c * 64 + lk;
  }

  float4v acc[4][4];
  #pragma unroll
  for (int rt = 0; rt < 4; rt++)
    #pragma unroll
    for (int ct = 0; ct < 4; ct++) acc[rt][ct] = (float4v){0.f, 0.f, 0.f, 0.f};

  #pragma unroll
  for (int ks = 0; ks < 64; ks += 32) {
    short8v a[4], b[4];
    #pragma unroll
    for (int rt = 0; rt < 4; rt++) a[rt] = *reinterpret_cast<const short8v*>(Aptr[rt] + ks);
    #pragma unroll
    for (int ct = 0; ct < 4; ct++)
      b[ct] = *reinterpret_cast<const short8v*>(Wz + (size_t)c * 4096 + (ct * 16 + lr) * 64 + ks + lk);
    #pragma unroll
    for (int rt = 0; rt < 4; rt++)
      #pragma unroll
      for (int ct = 0; ct < 4; ct++)
        acc[rt][ct] = __builtin_amdgcn_mfma_f32_16x16x32_bf16(a[rt], b[ct], acc[rt][ct], 0, 0, 0);
  }

  float sc[4], sh[4];
  #pragma unroll
  for (int ct = 0; ct < 4; ct++) {
    const int t = c * 64 + ct * 16 + lr;
    float mu = bnsum[t] * (1.f / NN);
    float var = bnsq[t] * (1.f / NN) - mu * mu;
    var = var > 0.f ? var : 0.f;
    float rs = rsqrtf(var + 1e-5f);
    sc[ct] = g[t] * rs;
    sh[ct] = bt[t] - mu * sc[ct];
  }

  #pragma unroll
  for (int rt = 0; rt < 4; rt++) {
    #pragma unroll
    for (int ct = 0; ct < 4; ct++) {
      const int col = c * 64 + ct * 16 + lr;
      #pragma unroll
      for (int r = 0; r < 4; r++) {
        const int rowl = rt * 16 + rbase + r;
        const int row = row0 + rowl;
        float h = fmaf(acc[rt][ct][r], sc[ct], sh[ct]);
        h = h > 0.f ? h : 0.f;
        if (row < NN) Hout[(size_t)row * 256 + col] = h;
        if (WITH_P2) h_lds[rowl][col] = f2bf(h);
      }
    }
  }

  if (WITH_P2) {
    __syncthreads();
    float4v acc2[4][4];
    #pragma unroll
    for (int rt = 0; rt < 4; rt++)
      #pragma unroll
      for (int ct = 0; ct < 4; ct++) acc2[rt][ct] = (float4v){0.f, 0.f, 0.f, 0.f};
    #pragma unroll
    for (int ks = 0; ks < 64; ks += 32) {
      short8v a[4], b[4];
      #pragma unroll
      for (int rt = 0; rt < 4; rt++)
        a[rt] = *reinterpret_cast<const short8v*>(&h_lds[rt * 16 + lr][c * 64 + ks + lk]);
      #pragma unroll
      for (int ct = 0; ct < 4; ct++)
        b[ct] = *reinterpret_cast<const short8v*>(Wp + (size_t)c * 4096 + (ct * 16 + lr) * 64 + ks + lk);
      #pragma unroll
      for (int rt = 0; rt < 4; rt++)
        #pragma unroll
        for (int ct = 0; ct < 4; ct++)
          acc2[rt][ct] = __builtin_amdgcn_mfma_f32_16x16x32_bf16(a[rt], b[ct], acc2[rt][ct], 0, 0, 0);
    }
    #pragma unroll
    for (int rt = 0; rt < 4; rt++) {
      #pragma unroll
      for (int ct = 0; ct < 4; ct++) {
        const int col = c * 64 + ct * 16 + lr;
        #pragma unroll
        for (int r = 0; r < 4; r++) {
          const int row = row0 + rt * 16 + rbase + r;
          if (row < NN) P2out[(size_t)row * 256 + col] = f2bf(acc2[rt][ct][r]);
        }
      }
    }
  }
}

// ---------------- launch ----------------

extern "C" void kernel_launch(void* const* d_in, const int* in_sizes, int n_in,
                              void* d_out, int out_size, void* d_ws, size_t ws_size,
                              hipStream_t stream) {
  const float* x    = (const float*)d_in[0];
  const int*   ei   = (const int*)d_in[1];
  const float* ew   = (const float*)d_in[2];
  const float* W1_0 = (const float*)d_in[3];
  const float* b1_0 = (const float*)d_in[4];
  const float* W2_0 = (const float*)d_in[5];
  // b2_* unused: BatchNorm cancels the pre-BN bias exactly
  const float* g0   = (const float*)d_in[7];
  const float* bt0  = (const float*)d_in[8];
  const float* W1_1 = (const float*)d_in[9];
  const float* b1_1 = (const float*)d_in[10];
  const float* W2_1 = (const float*)d_in[11];
  const float* g1   = (const float*)d_in[13];
  const float* bt1  = (const float*)d_in[14];
  const float* encW = (const float*)d_in[15];
  const float* encb = (const float*)d_in[16];

  const int* srcA = ei;
  const int* dstA = ei + NE;

  float* out_enc = (float*)d_out;
  float* out1 = out_enc + (size_t)NN * FDIM;
  float* out2 = out1 + (size_t)NN * FDIM;

  // P1 (bf16) lives in out1 region; P2 (bf16) in out2 region; Rb in ws.
  unsigned short* P1bf = (unsigned short*)out1;
  unsigned short* P2bf = (unsigned short*)out2;

  char* wp = (char*)d_ws;
  auto carve = [&](size_t bytes) {
    char* r = wp;
    wp += (bytes + 255) & ~(size_t)255;
    return r;
  };
  // deg16 (padded counters) + 4 BN accumulators carved adjacently -> one memset covers all
  int*   deg16   = (int*)carve((size_t)NN * 16 * 4);  // 3.2MB, one counter per 64B line
  float* bnsum0  = (float*)carve(256 * 4);
  float* bnsq0   = (float*)carve(256 * 4);
  float* bnsum1  = (float*)carve(256 * 4);
  float* bnsq1   = (float*)carve(256 * 4);
  int*   offs    = (int*)carve((size_t)(NN + 1) * 4);
  int*   rank    = (int*)carve((size_t)NE * 4);
  int*   partial = (int*)carve(SCAN_BLOCKS * 4);
  unsigned short* Bt1  = (unsigned short*)carve(256 * 256 * 2);
  unsigned short* BtE  = (unsigned short*)carve(256 * 256 * 2);
  unsigned short* Wb11 = (unsigned short*)carve(4 * 64 * 64 * 2);
  unsigned short* Wb20 = (unsigned short*)carve(4 * 64 * 64 * 2);
  unsigned short* Wb21 = (unsigned short*)carve(4 * 64 * 64 * 2);
  int4* recs           = (int4*)carve((size_t)NE * 16);
  unsigned short* Rb   = (unsigned short*)carve((size_t)NN * FDIM * 2);

  const size_t zspan = (((size_t)NN * 16 * 4 + 255) & ~(size_t)255) + 4 * 1024;
  hipMemsetAsync(deg16, 0, zspan, stream);

  // CSR build: hist produces per-edge ranks; scans build offs
  k_hist<<<HIST_BLOCKS, 256, 0, stream>>>(dstA, deg16, rank);
  k_scan_a<<<SCAN_BLOCKS, 256, 0, stream>>>(deg16, partial);
  k_scanb_wprep<<<257, 256, 0, stream>>>(partial, offs, W1_0, encW, W1_1, W2_0, W2_1,
                                         Bt1, BtE, Wb11, Wb20, Wb21);
  k_scan_c<<<SCAN_BLOCKS, 256, 0, stream>>>(deg16, partial, offs);

  // atomic-free record fill (4 edges/thread)
  k_fill<<<HIST_BLOCKS, 256, 0, stream>>>(srcA, dstA, ew, rank, offs, recs);

  // persistent weight-stationary GEMM: P1 + enc (x read once)
  k_mm<<<GRIDX, 512, 0, stream>>>(x, Bt1, BtE, encb, P1bf, out_enc);

  // layer 1
  k_agg<<<NN / 4, 256, 0, stream>>>(P1bf, offs, recs, b1_0, Rb);
  k_bd_stats<<<MMG, 256, 0, stream>>>(Rb, Wb20, bnsum0, bnsq0);
  k_bd_bn<1><<<MMG, 256, 0, stream>>>(Rb, Wb20, bnsum0, bnsq0, g0, bt0, Wb11, out1, P2bf);

  // layer 2
  k_agg<<<NN / 4, 256, 0, stream>>>(P2bf, offs, recs, b1_1, Rb);
  k_bd_stats<<<MMG, 256, 0, stream>>>(Rb, Wb21, bnsum1, bnsq1);
  k_bd_bn<0><<<MMG, 256, 0, stream>>>(Rb, Wb21, bnsum1, bnsq1, g1, bt1, nullptr, out2, nullptr);
}

// Round 20
// 326.037 us; speedup vs baseline: 1.0473x; 1.0473x over previous
//
#include <hip/hip_runtime.h>

#define NN 50000
#define NE 800000
#define FDIM 256
#define SCAN_BLOCKS 196  // ceil(50000/256)
#define MMG 782          // ceil(NN/64)  (bd kernels)
#define NTILE 1563       // ceil(NN/32)  (row tiles for k_mm)
#define GRIDX 256        // persistent k_mm blocks
#define HIST_BLOCKS 782  // ceil(NE/1024), 4 edges/thread

typedef __attribute__((ext_vector_type(8))) short short8v;
typedef __attribute__((ext_vector_type(4))) float float4v;

__device__ __forceinline__ unsigned short f2bf(float f) {
  unsigned u = __float_as_uint(f);
  unsigned r = (u + 0x7fffu + ((u >> 16) & 1u)) >> 16;
  return (unsigned short)r;
}
__device__ __forceinline__ float bf2f(unsigned short b) {
  return __uint_as_float(((unsigned)b) << 16);
}

// ---------------- CSR build ----------------

__global__ __launch_bounds__(256) void k_hist(const int* __restrict__ dst, int* __restrict__ deg16,
                                              int* __restrict__ rank) {
  const int base = blockIdx.x * 1024 + threadIdx.x;
  #pragma unroll
  for (int k = 0; k < 4; k++) {
    int e = base + k * 256;
    if (e < NE) rank[e] = atomicAdd(&deg16[dst[e] << 4], 1);
  }
}

__device__ __forceinline__ int block_incl_scan(int v, int* wsum) {
  const int tid = threadIdx.x;
  const int lane = tid & 63;
  const int w = tid >> 6;
  int incl = v;
  #pragma unroll
  for (int off = 1; off < 64; off <<= 1) {
    int tmp = __shfl_up(incl, off, 64);
    if (lane >= off) incl += tmp;
  }
  if (lane == 63) wsum[w] = incl;
  __syncthreads();
  int woff = 0;
  #pragma unroll
  for (int k = 0; k < 3; k++)
    if (k < w) woff += wsum[k];
  return woff + incl;
}

__global__ __launch_bounds__(256) void k_scan_a(const int* __restrict__ deg16, int* __restrict__ partial) {
  __shared__ int wsum[4];
  int i = blockIdx.x * 256 + threadIdx.x;
  int v = (i < NN) ? deg16[i << 4] : 0;
  int incl = block_incl_scan(v, wsum);
  if (threadIdx.x == 255) partial[blockIdx.x] = incl;
}

// blocks 0..255: weight prep (fp32->bf16, transposed); block 256: scan of partials
__global__ __launch_bounds__(256) void k_scanb_wprep(int* __restrict__ partial, int* __restrict__ offs,
                                                     const float* __restrict__ W1_0, const float* __restrict__ encW,
                                                     const float* __restrict__ W1_1, const float* __restrict__ W2_0,
                                                     const float* __restrict__ W2_1, unsigned short* __restrict__ Bt1,
                                                     unsigned short* __restrict__ BtE, unsigned short* __restrict__ Wb11,
                                                     unsigned short* __restrict__ Wb20, unsigned short* __restrict__ Wb21) {
  if (blockIdx.x == 256) {
    __shared__ int wsum[4];
    int tid = threadIdx.x;
    int v = (tid < SCAN_BLOCKS) ? partial[tid] : 0;
    int incl = block_incl_scan(v, wsum);
    if (tid < SCAN_BLOCKS) partial[tid] = incl - v;  // exclusive
    if (tid == 255) offs[NN] = incl;                 // total == NE
    return;
  }
  const int t = blockIdx.x;   // output col
  const int k = threadIdx.x;  // reduction index
  const int c = t >> 6, j = t & 63;
  Bt1[t * 256 + k] = f2bf(W1_0[c * 16384 + k * 64 + j]);
  BtE[t * 256 + k] = f2bf(encW[k * 256 + t]);
  if (k < 64) {
    Wb11[c * 4096 + j * 64 + k] = f2bf(W1_1[c * 4096 + k * 64 + j]);
    Wb20[c * 4096 + j * 64 + k] = f2bf(W2_0[c * 4096 + k * 64 + j]);
    Wb21[c * 4096 + j * 64 + k] = f2bf(W2_1[c * 4096 + k * 64 + j]);
  }
}

__global__ __launch_bounds__(256) void k_scan_c(const int* __restrict__ deg16, const int* __restrict__ partial,
                                                int* __restrict__ offs) {
  __shared__ int wsum[4];
  int i = blockIdx.x * 256 + threadIdx.x;
  int v = (i < NN) ? deg16[i << 4] : 0;
  int incl = block_incl_scan(v, wsum);
  int excl = partial[blockIdx.x] + incl - v;
  if (i < NN) offs[i] = excl;
}

// ---------------- atomic-free edge-record fill (standalone, 1 edge/thread) ----------------
__global__ __launch_bounds__(256) void k_fill(const int* __restrict__ srcA, const int* __restrict__ dstA,
                                              const float* __restrict__ ew, const int* __restrict__ rank,
                                              const int* __restrict__ offs, int4* __restrict__ recs) {
  int e = blockIdx.x * 256 + threadIdx.x;
  if (e < NE) {
    int sA = srcA[e];
    int dA = dstA[e];
    int rk = rank[e];
    unsigned p01 = (unsigned)f2bf(ew[e]) | ((unsigned)f2bf(ew[NE + e]) << 16);
    unsigned p23 = (unsigned)f2bf(ew[2 * NE + e]) | ((unsigned)f2bf(ew[3 * NE + e]) << 16);
    recs[offs[dA] + rk] = make_int4(sA, (int)p01, (int)p23, 0);
  }
}

// ---------------- persistent weight-stationary MFMA GEMM, P1 AND enc in one block ----------------
// 512 threads: waves 0..3 hold Bt1 fragments (P cols), waves 4..7 hold BtE (enc cols).
// x staged once per tile (double-buffered LDS); epilogues serialize through xs[cur].
__global__ __launch_bounds__(512) void k_mm(const float* __restrict__ x,
                                            const unsigned short* __restrict__ Bt1,
                                            const unsigned short* __restrict__ BtE,
                                            const float* __restrict__ encb,
                                            unsigned short* __restrict__ Pout,
                                            float* __restrict__ encout) {
  __shared__ __align__(16) unsigned short xs[2][32][264];  // 2 x 16896B
  const int tid = threadIdx.x;  // 0..511
  const int lane = tid & 63;
  const int w = tid >> 6;       // 0..7
  const int isE = w >> 2;       // waves 0-3: P, waves 4-7: enc
  const int colw = (w & 3) * 64;
  const int lr = lane & 15;
  const int lk = (lane >> 4) * 8;
  const int rbase = (lane >> 4) * 4;

  const unsigned short* Bt = isE ? BtE : Bt1;

  // B resident in registers: 32 fragments x 16B/lane = 128 VGPRs
  short8v bfrag[8][4];
  #pragma unroll
  for (int ks8 = 0; ks8 < 8; ks8++)
    #pragma unroll
    for (int ct = 0; ct < 4; ct++)
      bfrag[ks8][ct] = *reinterpret_cast<const short8v*>(
          Bt + (size_t)(colw + ct * 16 + lr) * 256 + ks8 * 32 + lk);

  float bv[4];
  #pragma unroll
  for (int ct = 0; ct < 4; ct++) bv[ct] = isE ? encb[colw + ct * 16 + lr] : 0.f;

  // prologue: stage first tile into buffer 0 (2048 float4 / 512 threads = 4 iters)
  {
    const int row0 = blockIdx.x * 32;
    #pragma unroll
    for (int it = 0; it < 4; it++) {
      int idx = it * 512 + tid;
      int grow = row0 + (idx >> 6);
      if (grow >= NN) grow = NN - 1;
      float4 v = *reinterpret_cast<const float4*>(x + (size_t)grow * 256 + (idx & 63) * 4);
      ushort4 o;
      o.x = f2bf(v.x); o.y = f2bf(v.y); o.z = f2bf(v.z); o.w = f2bf(v.w);
      *reinterpret_cast<ushort4*>(&xs[0][idx >> 6][(idx & 63) * 4]) = o;
    }
  }
  __syncthreads();

  int cur = 0;
  for (int t = blockIdx.x; t < NTILE; t += GRIDX, cur ^= 1) {
    const int row0 = t * 32;
    const int t2 = t + GRIDX;
    const bool hasNext = t2 < NTILE;

    // issue next tile's global loads (latency hides under MFMAs below)
    float4 xv[4];
    if (hasNext) {
      #pragma unroll
      for (int it = 0; it < 4; it++) {
        int idx = it * 512 + tid;
        int grow = t2 * 32 + (idx >> 6);
        if (grow >= NN) grow = NN - 1;
        xv[it] = *reinterpret_cast<const float4*>(x + (size_t)grow * 256 + (idx & 63) * 4);
      }
    }

    // MFMA: A from LDS, B from registers
    float4v acc[2][4];
    #pragma unroll
    for (int rt = 0; rt < 2; rt++)
      #pragma unroll
      for (int ct = 0; ct < 4; ct++) acc[rt][ct] = (float4v){0.f, 0.f, 0.f, 0.f};

    #pragma unroll
    for (int ks8 = 0; ks8 < 8; ks8++) {
      short8v a[2];
      #pragma unroll
      for (int rt = 0; rt < 2; rt++)
        a[rt] = *reinterpret_cast<const short8v*>(&xs[cur][rt * 16 + lr][ks8 * 32 + lk]);
      #pragma unroll
      for (int rt = 0; rt < 2; rt++)
        #pragma unroll
        for (int ct = 0; ct < 4; ct++)
          acc[rt][ct] = __builtin_amdgcn_mfma_f32_16x16x32_bf16(a[rt], bfrag[ks8][ct], acc[rt][ct], 0, 0, 0);
    }

    __syncthreads();  // xs[cur] reads done

    // stage next tile into the other buffer
    if (hasNext) {
      #pragma unroll
      for (int it = 0; it < 4; it++) {
        int idx = it * 512 + tid;
        ushort4 o;
        o.x = f2bf(xv[it].x); o.y = f2bf(xv[it].y); o.z = f2bf(xv[it].z); o.w = f2bf(xv[it].w);
        *reinterpret_cast<ushort4*>(&xs[cur ^ 1][idx >> 6][(idx & 63) * 4]) = o;
      }
    }

    // ---- epilogue phase 1: P (bf16) through xs[cur] ----
    if (!isE) {
      #pragma unroll
      for (int rt = 0; rt < 2; rt++)
        #pragma unroll
        for (int ct = 0; ct < 4; ct++) {
          const int col = colw + ct * 16 + lr;
          #pragma unroll
          for (int r = 0; r < 4; r++) xs[cur][rt * 16 + rbase + r][col] = f2bf(acc[rt][ct][r]);
        }
    }
    __syncthreads();
    #pragma unroll
    for (int it = 0; it < 2; it++) {
      int idx = it * 512 + tid;  // 32 rows x 32 chunks of 8 shorts = 1024
      int row = idx >> 5;
      int p = idx & 31;
      if (row0 + row < NN)
        *reinterpret_cast<short8v*>(Pout + (size_t)(row0 + row) * 256 + p * 8) =
            *reinterpret_cast<const short8v*>(&xs[cur][row][p * 8]);
    }
    __syncthreads();

    // ---- epilogue phase 2: enc (fp32), two 128-col phases through xs[cur] ----
    float (*cs)[132] = reinterpret_cast<float(*)[132]>(&xs[cur][0][0]);  // 32*132*4 = 16896B
    #pragma unroll
    for (int ph = 0; ph < 2; ph++) {
      if (isE && (colw >> 7) == ph) {
        #pragma unroll
        for (int rt = 0; rt < 2; rt++)
          #pragma unroll
          for (int ct = 0; ct < 4; ct++) {
            const int col = colw + ct * 16 + lr - ph * 128;
            #pragma unroll
            for (int r = 0; r < 4; r++) cs[rt * 16 + rbase + r][col] = acc[rt][ct][r] + bv[ct];
          }
      }
      __syncthreads();
      #pragma unroll
      for (int it = 0; it < 2; it++) {
        int idx = it * 512 + tid;  // 32 rows x 32 float4 chunks = 1024
        int row = idx >> 5;
        int p = idx & 31;
        if (row0 + row < NN)
          *reinterpret_cast<float4*>(encout + (size_t)(row0 + row) * 256 + ph * 128 + p * 4) =
              *reinterpret_cast<const float4*>(&cs[row][p * 4]);
      }
      __syncthreads();
    }
  }
}

// ---------------- aggregation: one wave per node, half-waves on even/odd edges ----------------
__global__ __launch_bounds__(256) void k_agg(const unsigned short* __restrict__ P,
                                             const int* __restrict__ offs, const int4* __restrict__ recs,
                                             const float* __restrict__ b1, unsigned short* __restrict__ Rb) {
  const int lane = threadIdx.x & 63;
  const int wid = threadIdx.x >> 6;
  const int i = blockIdx.x * 4 + wid;  // grid = NN/4 exactly
  const int half = lane >> 5;
  const int l32 = lane & 31;
  const int col0 = l32 * 8;
  const int c = l32 >> 3;

  const int es = offs[i], ee = offs[i + 1];
  float acc[8];
  #pragma unroll
  for (int j = 0; j < 8; j++) acc[j] = 0.f;

  for (int base = es; base < ee; base += 16) {
    int sq[8];
    float wq[8];
    #pragma unroll
    for (int q = 0; q < 8; q++) {
      int e = base + 2 * q + half;
      bool valid = e < ee;
      int4 rv = recs[valid ? e : es];
      sq[q] = rv.x;
      unsigned p = (c < 2) ? (unsigned)rv.y : (unsigned)rv.z;
      unsigned short wb = (c & 1) ? (unsigned short)(p >> 16) : (unsigned short)(p & 0xffff);
      wq[q] = valid ? bf2f(wb) : 0.f;
    }
    short8v pq[8];
    #pragma unroll
    for (int q = 0; q < 8; q++)
      pq[q] = *reinterpret_cast<const short8v*>(P + (size_t)sq[q] * 256 + col0);
    #pragma unroll
    for (int q = 0; q < 8; q++)
      #pragma unroll
      for (int j = 0; j < 8; j++)
        acc[j] = fmaf(wq[q], bf2f((unsigned short)pq[q][j]), acc[j]);
  }

  #pragma unroll
  for (int j = 0; j < 8; j++) acc[j] += __shfl_xor(acc[j], 32);

  if (half == 0) {
    short8v ps = *reinterpret_cast<const short8v*>(P + (size_t)i * 256 + col0);
    float4 b4a = *reinterpret_cast<const float4*>(b1 + col0);
    float4 b4b = *reinterpret_cast<const float4*>(b1 + col0 + 4);
    float bb[8] = {b4a.x, b4a.y, b4a.z, b4a.w, b4b.x, b4b.y, b4b.z, b4b.w};
    short8v out;
    #pragma unroll
    for (int j = 0; j < 8; j++) {
      float r = bf2f((unsigned short)ps[j]) + acc[j] + bb[j];
      out[j] = (short)f2bf(r > 0.f ? r : 0.f);
    }
    *reinterpret_cast<short8v*>(Rb + (size_t)i * 256 + col0) = out;
  }
}

// ---------------- block-diag K=64 GEMM: stats-only pass (b2 cancels in BN) ----------------
__global__ __launch_bounds__(256) void k_bd_stats(const unsigned short* __restrict__ A,
                                                  const unsigned short* __restrict__ Wz,
                                                  float* __restrict__ bnsum, float* __restrict__ bnsq) {
  const int lane = threadIdx.x & 63;
  const int c = threadIdx.x >> 6;
  const int row0 = blockIdx.x * 64;
  const int lr = lane & 15;
  const int lk = (lane >> 4) * 8;

  const unsigned short* Aptr[4];
  #pragma unroll
  for (int rt = 0; rt < 4; rt++) {
    int row = row0 + rt * 16 + lr;
    if (row >= NN) row = NN - 1;
    Aptr[rt] = A + (size_t)row * 256 + c * 64 + lk;
  }

  float4v acc[4][4];
  #pragma unroll
  for (int rt = 0; rt < 4; rt++)
    #pragma unroll
    for (int ct = 0; ct < 4; ct++) acc[rt][ct] = (float4v){0.f, 0.f, 0.f, 0.f};

  #pragma unroll
  for (int ks = 0; ks < 64; ks += 32) {
    short8v a[4], b[4];
    #pragma unroll
    for (int rt = 0; rt < 4; rt++) a[rt] = *reinterpret_cast<const short8v*>(Aptr[rt] + ks);
    #pragma unroll
    for (int ct = 0; ct < 4; ct++)
      b[ct] = *reinterpret_cast<const short8v*>(Wz + (size_t)c * 4096 + (ct * 16 + lr) * 64 + ks + lk);
    #pragma unroll
    for (int rt = 0; rt < 4; rt++)
      #pragma unroll
      for (int ct = 0; ct < 4; ct++)
        acc[rt][ct] = __builtin_amdgcn_mfma_f32_16x16x32_bf16(a[rt], b[ct], acc[rt][ct], 0, 0, 0);
  }

  #pragma unroll
  for (int ct = 0; ct < 4; ct++) {
    const int col = c * 64 + ct * 16 + lr;
    float s1 = 0.f, s2 = 0.f;
    #pragma unroll
    for (int rt = 0; rt < 4; rt++) {
      #pragma unroll
      for (int r = 0; r < 4; r++) {
        const int row = row0 + rt * 16 + (lane >> 4) * 4 + r;
        if (row < NN) {
          float v = acc[rt][ct][r];
          s1 += v;
          s2 += v * v;
        }
      }
    }
    s1 += __shfl_xor(s1, 16); s1 += __shfl_xor(s1, 32);
    s2 += __shfl_xor(s2, 16); s2 += __shfl_xor(s2, 32);
    if (lane < 16) {
      atomicAdd(&bnsum[col], s1);
      atomicAdd(&bnsq[col], s2);
    }
  }
}

// ---------------- block-diag K=64 GEMM: recompute + BN + relu; optional fused P2 ----------------
template <int WITH_P2>
__global__ __launch_bounds__(256) void k_bd_bn(const unsigned short* __restrict__ A,
                                               const unsigned short* __restrict__ Wz,
                                               const float* __restrict__ bnsum, const float* __restrict__ bnsq,
                                               const float* __restrict__ g, const float* __restrict__ bt,
                                               const unsigned short* __restrict__ Wp,
                                               float* __restrict__ Hout, unsigned short* __restrict__ P2out) {
  __shared__ __align__(16) unsigned short h_lds[64][264];  // stride 528B
  const int lane = threadIdx.x & 63;
  const int c = threadIdx.x >> 6;
  const int row0 = blockIdx.x * 64;
  const int lr = lane & 15;
  const int lk = (lane >> 4) * 8;
  const int rbase = (lane >> 4) * 4;

  const unsigned short* Aptr[4];
  #pragma unroll
  for (int rt = 0; rt < 4; rt++) {
    int row = row0 + rt * 16 + lr;
    if (row >= NN) row = NN - 1;
    Aptr[rt] = A + (size_t)row * 256 + c * 64 + lk;
  }

  float4v acc[4][4];
  #pragma unroll
  for (int rt = 0; rt < 4; rt++)
    #pragma unroll
    for (int ct = 0; ct < 4; ct++) acc[rt][ct] = (float4v){0.f, 0.f, 0.f, 0.f};

  #pragma unroll
  for (int ks = 0; ks < 64; ks += 32) {
    short8v a[4], b[4];
    #pragma unroll
    for (int rt = 0; rt < 4; rt++) a[rt] = *reinterpret_cast<const short8v*>(Aptr[rt] + ks);
    #pragma unroll
    for (int ct = 0; ct < 4; ct++)
      b[ct] = *reinterpret_cast<const short8v*>(Wz + (size_t)c * 4096 + (ct * 16 + lr) * 64 + ks + lk);
    #pragma unroll
    for (int rt = 0; rt < 4; rt++)
      #pragma unroll
      for (int ct = 0; ct < 4; ct++)
        acc[rt][ct] = __builtin_amdgcn_mfma_f32_16x16x32_bf16(a[rt], b[ct], acc[rt][ct], 0, 0, 0);
  }

  float sc[4], sh[4];
  #pragma unroll
  for (int ct = 0; ct < 4; ct++) {
    const int t = c * 64 + ct * 16 + lr;
    float mu = bnsum[t] * (1.f / NN);
    float var = bnsq[t] * (1.f / NN) - mu * mu;
    var = var > 0.f ? var : 0.f;
    float rs = rsqrtf(var + 1e-5f);
    sc[ct] = g[t] * rs;
    sh[ct] = bt[t] - mu * sc[ct];
  }

  #pragma unroll
  for (int rt = 0; rt < 4; rt++) {
    #pragma unroll
    for (int ct = 0; ct < 4; ct++) {
      const int col = c * 64 + ct * 16 + lr;
      #pragma unroll
      for (int r = 0; r < 4; r++) {
        const int rowl = rt * 16 + rbase + r;
        const int row = row0 + rowl;
        float h = fmaf(acc[rt][ct][r], sc[ct], sh[ct]);
        h = h > 0.f ? h : 0.f;
        if (row < NN) Hout[(size_t)row * 256 + col] = h;
        if (WITH_P2) h_lds[rowl][col] = f2bf(h);
      }
    }
  }

  if (WITH_P2) {
    __syncthreads();
    float4v acc2[4][4];
    #pragma unroll
    for (int rt = 0; rt < 4; rt++)
      #pragma unroll
      for (int ct = 0; ct < 4; ct++) acc2[rt][ct] = (float4v){0.f, 0.f, 0.f, 0.f};
    #pragma unroll
    for (int ks = 0; ks < 64; ks += 32) {
      short8v a[4], b[4];
      #pragma unroll
      for (int rt = 0; rt < 4; rt++)
        a[rt] = *reinterpret_cast<const short8v*>(&h_lds[rt * 16 + lr][c * 64 + ks + lk]);
      #pragma unroll
      for (int ct = 0; ct < 4; ct++)
        b[ct] = *reinterpret_cast<const short8v*>(Wp + (size_t)c * 4096 + (ct * 16 + lr) * 64 + ks + lk);
      #pragma unroll
      for (int rt = 0; rt < 4; rt++)
        #pragma unroll
        for (int ct = 0; ct < 4; ct++)
          acc2[rt][ct] = __builtin_amdgcn_mfma_f32_16x16x32_bf16(a[rt], b[ct], acc2[rt][ct], 0, 0, 0);
    }
    #pragma unroll
    for (int rt = 0; rt < 4; rt++) {
      #pragma unroll
      for (int ct = 0; ct < 4; ct++) {
        const int col = c * 64 + ct * 16 + lr;
        #pragma unroll
        for (int r = 0; r < 4; r++) {
          const int row = row0 + rt * 16 + rbase + r;
          if (row < NN) P2out[(size_t)row * 256 + col] = f2bf(acc2[rt][ct][r]);
        }
      }
    }
  }
}

// ---------------- launch ----------------

extern "C" void kernel_launch(void* const* d_in, const int* in_sizes, int n_in,
                              void* d_out, int out_size, void* d_ws, size_t ws_size,
                              hipStream_t stream) {
  const float* x    = (const float*)d_in[0];
  const int*   ei   = (const int*)d_in[1];
  const float* ew   = (const float*)d_in[2];
  const float* W1_0 = (const float*)d_in[3];
  const float* b1_0 = (const float*)d_in[4];
  const float* W2_0 = (const float*)d_in[5];
  // b2_* unused: BatchNorm cancels the pre-BN bias exactly
  const float* g0   = (const float*)d_in[7];
  const float* bt0  = (const float*)d_in[8];
  const float* W1_1 = (const float*)d_in[9];
  const float* b1_1 = (const float*)d_in[10];
  const float* W2_1 = (const float*)d_in[11];
  const float* g1   = (const float*)d_in[13];
  const float* bt1  = (const float*)d_in[14];
  const float* encW = (const float*)d_in[15];
  const float* encb = (const float*)d_in[16];

  const int* srcA = ei;
  const int* dstA = ei + NE;

  float* out_enc = (float*)d_out;
  float* out1 = out_enc + (size_t)NN * FDIM;
  float* out2 = out1 + (size_t)NN * FDIM;

  // P1 (bf16) lives in out1 region; P2 (bf16) in out2 region; Rb in ws.
  unsigned short* P1bf = (unsigned short*)out1;
  unsigned short* P2bf = (unsigned short*)out2;

  char* wp = (char*)d_ws;
  auto carve = [&](size_t bytes) {
    char* r = wp;
    wp += (bytes + 255) & ~(size_t)255;
    return r;
  };
  // deg16 (padded counters) + 4 BN accumulators carved adjacently -> one memset covers all
  int*   deg16   = (int*)carve((size_t)NN * 16 * 4);  // 3.2MB, one counter per 64B line
  float* bnsum0  = (float*)carve(256 * 4);
  float* bnsq0   = (float*)carve(256 * 4);
  float* bnsum1  = (float*)carve(256 * 4);
  float* bnsq1   = (float*)carve(256 * 4);
  int*   offs    = (int*)carve((size_t)(NN + 1) * 4);
  int*   rank    = (int*)carve((size_t)NE * 4);
  int*   partial = (int*)carve(SCAN_BLOCKS * 4);
  unsigned short* Bt1  = (unsigned short*)carve(256 * 256 * 2);
  unsigned short* BtE  = (unsigned short*)carve(256 * 256 * 2);
  unsigned short* Wb11 = (unsigned short*)carve(4 * 64 * 64 * 2);
  unsigned short* Wb20 = (unsigned short*)carve(4 * 64 * 64 * 2);
  unsigned short* Wb21 = (unsigned short*)carve(4 * 64 * 64 * 2);
  int4* recs           = (int4*)carve((size_t)NE * 16);
  unsigned short* Rb   = (unsigned short*)carve((size_t)NN * FDIM * 2);

  const size_t zspan = (((size_t)NN * 16 * 4 + 255) & ~(size_t)255) + 4 * 1024;
  hipMemsetAsync(deg16, 0, zspan, stream);

  // CSR build: hist produces per-edge ranks; scans build offs
  k_hist<<<HIST_BLOCKS, 256, 0, stream>>>(dstA, deg16, rank);
  k_scan_a<<<SCAN_BLOCKS, 256, 0, stream>>>(deg16, partial);
  k_scanb_wprep<<<257, 256, 0, stream>>>(partial, offs, W1_0, encW, W1_1, W2_0, W2_1,
                                         Bt1, BtE, Wb11, Wb20, Wb21);
  k_scan_c<<<SCAN_BLOCKS, 256, 0, stream>>>(deg16, partial, offs);

  // atomic-free record fill
  k_fill<<<(NE + 255) / 256, 256, 0, stream>>>(srcA, dstA, ew, rank, offs, recs);

  // persistent weight-stationary GEMM: P1 + enc (x read once)
  k_mm<<<GRIDX, 512, 0, stream>>>(x, Bt1, BtE, encb, P1bf, out_enc);

  // layer 1
  k_agg<<<NN / 4, 256, 0, stream>>>(P1bf, offs, recs, b1_0, Rb);
  k_bd_stats<<<MMG, 256, 0, stream>>>(Rb, Wb20, bnsum0, bnsq0);
  k_bd_bn<1><<<MMG, 256, 0, stream>>>(Rb, Wb20, bnsum0, bnsq0, g0, bt0, Wb11, out1, P2bf);

  // layer 2
  k_agg<<<NN / 4, 256, 0, stream>>>(P2bf, offs, recs, b1_1, Rb);
  k_bd_stats<<<MMG, 256, 0, stream>>>(Rb, Wb21, bnsum1, bnsq1);
  k_bd_bn<0><<<MMG, 256, 0, stream>>>(Rb, Wb21, bnsum1, bnsq1, g1, bt1, nullptr, out2, nullptr);
}